// Round 10
// baseline (28.501 us; speedup 1.0000x reference)
//
#include <hip/hip_runtime.h>
#include <math.h>

// ChamferLossSplitPID: B=512, N=M=256, D=4, PIDs 0..3.
// out[0] = sum_b(sum_{p=1..3} loss_p)/B ; out[1+b] = (sum_{out_pid==0} |y|)/max(c0,1)/B
//
// R10: R9 main kernel (pid-scatter + sorted-thread mapping, 512 threads,
// unroll-4) with the reduce kernel fused away: per-block loss atomicAdd'ed to
// out[0], which a 4-byte memset node re-zeros each replay. One dispatch fewer;
// the adds overlap main-kernel execution instead of serializing after it.

constexpr int BATCH = 512;
constexpr int NP    = 256;
constexpr float INF2 = 1e30f;

__device__ __forceinline__ float dist2_f4(const float4 a, const float4 b) {
    const float dx = a.x - b.x;
    const float dy = a.y - b.y;
    const float dz = a.z - b.z;
    const float dw = a.w - b.w;
    return dx * dx + dy * dy + dz * dz + dw * dw;
}

__device__ __forceinline__ float min_scan(const float4 xp, const float4* seg, int cnt) {
    float m0 = INF2, m1 = INF2, m2 = INF2, m3 = INF2;
    int j = 0;
    for (; j + 4 <= cnt; j += 4) {      // 4 independent LDS loads + dist chains
        const float4 A = seg[j], B = seg[j + 1], C = seg[j + 2], D = seg[j + 3];
        m0 = fminf(m0, dist2_f4(xp, A));
        m1 = fminf(m1, dist2_f4(xp, B));
        m2 = fminf(m2, dist2_f4(xp, C));
        m3 = fminf(m3, dist2_f4(xp, D));
    }
    for (; j < cnt; ++j) m0 = fminf(m0, dist2_f4(xp, seg[j]));
    return fminf(fminf(m0, m1), fminf(m2, m3));
}

__global__ __launch_bounds__(512) void chamfer_pid_kernel(
    const float* __restrict__ target,   // [B, NP, 4]
    const float* __restrict__ reco,     // [B, NP, 4]
    const int*   __restrict__ in_pid,   // [B, NP]
    const int*   __restrict__ out_pid,  // [B, NP]
    float* __restrict__ out)            // [1 + B]
{
    const int b    = blockIdx.x;
    const int tid  = threadIdx.x;
    const int k    = tid & (NP - 1);
    const int half = tid >> 8;          // 0: x-role, 1: y-role

    __shared__ float4 sxs[NP], sys[NP];
    __shared__ int   s_cx[4], s_cy[4], s_offx[4], s_offy[4];
    __shared__ float s_sxy[4], s_syx[4], s_snx[4], s_sny[4];

    if (tid < 4) {
        s_cx[tid] = 0;    s_cy[tid] = 0;
        s_sxy[tid] = 0.f; s_syx[tid] = 0.f;
        s_snx[tid] = 0.f; s_sny[tid] = 0.f;
    }
    __syncthreads();

    // ---- load + slot-grab (half 0 loads x, half 1 loads y) ----
    float4 pt;
    int pid, slot;
    if (half == 0) {
        pt  = reinterpret_cast<const float4*>(target)[(size_t)b * NP + k];
        pid = in_pid[(size_t)b * NP + k];
        slot = atomicAdd(&s_cx[pid], 1);
    } else {
        pt  = reinterpret_cast<const float4*>(reco)[(size_t)b * NP + k];
        pid = out_pid[(size_t)b * NP + k];
        slot = atomicAdd(&s_cy[pid], 1);
    }
    __syncthreads();

    if (tid == 0) {
        int ox = 0, oy = 0;
        #pragma unroll
        for (int q = 0; q < 4; ++q) {
            s_offx[q] = ox; ox += s_cx[q];
            s_offy[q] = oy; oy += s_cy[q];
        }
    }
    __syncthreads();

    if (half == 0) sxs[s_offx[pid] + slot] = pt;
    else           sys[s_offy[pid] + slot] = pt;
    __syncthreads();

    // ---- phase B: thread k owns SORTED point k (wave-coherent pid) ----
    if (half == 0) {
        const int p = (k >= s_offx[1]) + (k >= s_offx[2]) + (k >= s_offx[3]);
        const float4 xp = sxs[k];
        if (p >= 1) {
            const float nrm = sqrtf(xp.x * xp.x + xp.y * xp.y + xp.z * xp.z + xp.w * xp.w);
            atomicAdd(&s_snx[p], nrm);
            const int cnt = s_cy[p];
            if (cnt > 0) {
                const float mn = min_scan(xp, (const float4*)&sys[s_offy[p]], cnt);
                atomicAdd(&s_sxy[p], sqrtf(mn));   // sqrt(min d2) == min dist
            }
        }
    } else {
        const int p = (k >= s_offy[1]) + (k >= s_offy[2]) + (k >= s_offy[3]);
        const float4 yp = sys[k];
        const float nrm = sqrtf(yp.x * yp.x + yp.y * yp.y + yp.z * yp.z + yp.w * yp.w);
        atomicAdd(&s_sny[p], nrm);                 // pid 0 needed for output 1
        if (p >= 1) {
            const int cnt = s_cx[p];
            if (cnt > 0) {
                const float mn = min_scan(yp, (const float4*)&sxs[s_offx[p]], cnt);
                atomicAdd(&s_syx[p], sqrtf(mn));
            }
        }
    }
    __syncthreads();

    if (tid == 0) {
        float nonzero = 0.0f;
        #pragma unroll
        for (int q = 1; q < 4; ++q) {
            const int cxq = s_cx[q];
            const int cyq = s_cy[q];
            const float n_in  = (float)(cxq > 1 ? cxq : 1);
            const float n_out = (float)(cyq > 1 ? cyq : 1);
            float loss;
            if (cyq == 0) {
                loss = s_snx[q] / n_in;
            } else if (cxq == 0) {
                loss = s_sny[q] / n_out;
            } else {
                loss = 0.5f * (s_sxy[q] / n_out + s_syx[q] / n_in);
            }
            nonzero += loss;
        }
        atomicAdd(out, nonzero * (1.0f / (float)BATCH));   // fused reduction

        const int c0 = s_cy[0];
        const float c0f = (float)(c0 > 1 ? c0 : 1);
        out[1 + b] = (s_sny[0] / c0f) / (float)BATCH;
    }
}

extern "C" void kernel_launch(void* const* d_in, const int* in_sizes, int n_in,
                              void* d_out, int out_size, void* d_ws, size_t ws_size,
                              hipStream_t stream) {
    const float* target  = (const float*)d_in[0];
    const float* reco    = (const float*)d_in[1];
    const int*   in_pid  = (const int*)d_in[2];
    const int*   out_pid = (const int*)d_in[3];
    float* out = (float*)d_out;

    // re-zero the fused-reduction accumulator each call (memset node in graph)
    hipMemsetAsync(out, 0, sizeof(float), stream);
    chamfer_pid_kernel<<<BATCH, 512, 0, stream>>>(target, reco, in_pid, out_pid, out);
}